// Round 11
// baseline (278.667 us; speedup 1.0000x reference)
//
#include <hip/hip_runtime.h>

typedef unsigned int u32;
typedef unsigned short u16;
typedef unsigned char u8;
typedef long i64;
typedef __attribute__((ext_vector_type(8))) short short8;
typedef __attribute__((ext_vector_type(4))) float f32x4;

#define MAXBIN 1024   // bins of 128 dsts; N=100k -> 782 bins
#define SORT_TPB 1024 // threads/block for scatter: 16 waves/block for latency hiding
#define BINCAP 4096   // fixed binned capacity/bin: mean 2046, sigma~45 -> 45-sigma headroom
#define CSRCAP 5120   // fixed padded-csr capacity/bin: max padded = bincnt + 128*8 <= ~3300
#define PPW 4         // pairs per persistent agg wave (cross-pair software pipeline)

__device__ inline u16 f2bf(float f) {
    u32 u = __builtin_bit_cast(u32, f);
    u32 r = (u + 0x7fffu + ((u >> 16) & 1u)) >> 16;  // RTNE
    return (u16)r;
}

// MFMA-as-summation. A fragment = gathered fp8 rows (lane&15 = A-row m,
// lane>>4 = k-group/edge slot, 8 bytes per lane). B selector routes byte n of
// selected k-groups into column n. C[m][n] accumulates feature sums.
__device__ inline f32x4 mfma_fp8(uint2 a, uint2 b, f32x4 c) {
    return __builtin_amdgcn_mfma_f32_16x16x32_fp8_fp8(
        __builtin_bit_cast(i64, a), __builtin_bit_cast(i64, b), c, 0, 0, 0);
}

// Output-feature permutation induced by the MFMA C layout. Position p in the stored
// row holds true feature pi(p); pi is baked into wt2/wt3 k-dim (exact, free).
__device__ inline int permP(int p) {
    return ((p >> 5) << 5) + ((p & 3) << 3) + ((p >> 2) & 7);
}

// ---------- CSR build ----------
// R1: direct random 4B scatter = 106MB WRITE_SIZE (16x line amplification) -> binned.
// R2: 1024 threads/block fixed the occupancy latency bound.
// R8: fixed-capacity bins (BINCAP) killed k_bhist + k_bscan (-13us).
__global__ __launch_bounds__(SORT_TPB) void k_bscatter(const int* __restrict__ ei, int E, int W,
                                                       int* __restrict__ binCnt,
                                                       u32* __restrict__ binned, int NBIN) {
    __shared__ int lh[MAXBIN];
    __shared__ int lb[MAXBIN];
    int tid = threadIdx.x;
    for (int i = tid; i < NBIN; i += SORT_TPB) lh[i] = 0;
    __syncthreads();
    int s = blockIdx.x * W, e = min(E, s + W);
    for (int j = s + tid; j < e; j += SORT_TPB) atomicAdd(&lh[ei[E + j] >> 7], 1);
    __syncthreads();
    for (int i = tid; i < NBIN; i += SORT_TPB) {
        int h = lh[i];
        int base = 0;
        if (h) {
            base = atomicAdd(&binCnt[i], h);
            if (base + h > BINCAP) base = BINCAP - h;  // fault-safety clamp (never expected)
        }
        lb[i] = i * BINCAP + base;
    }
    __syncthreads();
    for (int i = tid; i < NBIN; i += SORT_TPB) lh[i] = 0;
    __syncthreads();
    for (int j = s + tid; j < e; j += SORT_TPB) {
        int d = ei[E + j];
        int b = d >> 7;
        int r = atomicAdd(&lh[b], 1);
        binned[lb[b] + r] = ((u32)ei[j] << 7) | (u32)(d & 127);
    }
}

// Padded CSR at fixed per-bin base b*CSRCAP: per-dst slots pc = (c+1 self) rounded
// up to 8. Region sentinel-filled (N) over the used length, then self + real edges
// overwrite. offs[d] = start, ends[d] = start + pc (exact mult-8 range).
__global__ __launch_bounds__(256) void k_bcsr(const u32* __restrict__ binned,
                                              const int* __restrict__ binCnt,
                                              int N, int* __restrict__ offs,
                                              int* __restrict__ ends,
                                              float* __restrict__ dinv,
                                              int* __restrict__ csr) {
    __shared__ int cnt[128];
    __shared__ int off[128];
    __shared__ int tot;
    __shared__ int fillEnd;
    int b = blockIdx.x;
    int tid = threadIdx.x;
    int dLo = b << 7;
    int nd = min(128, N - dLo);
    int bbase = b * BINCAP;
    int gCnt = min(binCnt[b], BINCAP);
    int pbase = b * CSRCAP;
    if (tid < 128) cnt[tid] = 0;
    __syncthreads();
    for (int j = tid; j < gCnt; j += 256) atomicAdd(&cnt[binned[bbase + j] & 127u], 1);
    __syncthreads();
    int c = (tid < 128) ? cnt[tid] : 0;
    int pc = (tid < 128) ? ((c + 8) & ~7) : 0;  // (c+1 self) rounded up to 8
    int lane = tid & 63;
    int isc = pc;
    for (int d = 1; d < 64; d <<= 1) { int o = __shfl_up(isc, d, 64); if (lane >= d) isc += o; }
    if (tid == 63) tot = isc;
    __syncthreads();
    int add = (tid >= 64 && tid < 128) ? tot : 0;
    if (tid < 128) off[tid] = add + isc - pc;
    if (tid == 127) fillEnd = add + isc;  // total padded length for this bin
    __syncthreads();
    // sentinel-fill used padded region only
    for (int j = tid; j < fillEnd; j += 256) csr[pbase + j] = N;
    __syncthreads();
    if (tid < nd) {
        offs[dLo + tid] = pbase + off[tid];
        ends[dLo + tid] = pbase + off[tid] + pc;
        dinv[dLo + tid] = rsqrtf((float)(c + 1));
        csr[pbase + off[tid] + c] = dLo + tid;  // self-loop entry
    }
    if (tid < 128) cnt[tid] = 0;
    __syncthreads();
    for (int j = tid; j < gCnt; j += 256) {
        u32 v = binned[bbase + j];
        int d7 = (int)(v & 127u);
        int r = atomicAdd(&cnt[d7], 1);
        csr[pbase + off[d7] + r] = (int)(v >> 7);
    }
}

// ---------- fused weight converts (W[K][M] row-major -> Wt[M][K] bf16) ----------
// wt2/wt3 k-dim permuted by pi (agg128 stores feature pi(p) at position p).
__global__ void k_wtall(const float* __restrict__ W1, const float* __restrict__ W2,
                        const float* __restrict__ W3, u16* __restrict__ wt1,
                        u16* __restrict__ wt2, u16* __restrict__ wt3) {
    int idx = blockIdx.x * 256 + threadIdx.x;
    if (idx < 16384) {
        int k = idx >> 7, m = idx & 127;
        wt1[m * 128 + k] = f2bf(W1[idx]);
    } else if (idx < 32768) {
        int i = idx - 16384, p = i >> 7, m = i & 127;
        wt2[m * 128 + p] = f2bf(W2[permP(p) * 128 + m]);
    } else if (idx < 40960) {
        int i = idx - 32768, p = i >> 6, m = i & 63;
        wt3[m * 128 + p] = f2bf(W3[permP(p) * 64 + m]);
    }
}

// ---------- GEMM: g8 = fp8((x @ W) * dinv[row] * 16); also zeroes sentinel row N --
template <int M, bool F32IN>
__global__ __launch_bounds__(256) void k_gemm(const void* __restrict__ xin,
                                              const u16* __restrict__ wt,
                                              const float* __restrict__ dinv,
                                              u8* __restrict__ g8, int N) {
    constexpr int K = 128;
    constexpr int LDK = 136;
    __shared__ u16 lwt[M * LDK];
    int tid = threadIdx.x;
    if (blockIdx.x == 0 && tid < M / 16)  // keep sentinel row zero for padded agg
        *(uint4*)(g8 + (size_t)N * M + (size_t)tid * 16) = make_uint4(0u, 0u, 0u, 0u);
    const uint4* wsrc = (const uint4*)wt;
#pragma unroll
    for (int c = tid; c < M * K / 8; c += 256) {
        int row = c >> 4, kc = c & 15;
        *(uint4*)&lwt[row * LDK + kc * 8] = wsrc[c];
    }
    __syncthreads();
    int lane = tid & 63, wv = tid >> 6;
    int node = blockIdx.x * 64 + wv * 16 + (lane & 15);
    int nodec = min(node, N - 1);
    int kr = (lane >> 4) * 8;
    f32x4 acc[M / 16];
#pragma unroll
    for (int t = 0; t < M / 16; t++) acc[t] = (f32x4){0.f, 0.f, 0.f, 0.f};
#pragma unroll
    for (int ks = 0; ks < 4; ks++) {
        short8 bfr;
        if (F32IN) {
            const float* xr = (const float*)xin + (size_t)nodec * K + ks * 32 + kr;
            float4 fa = *(const float4*)xr;
            float4 fb = *(const float4*)(xr + 4);
            bfr = (short8){(short)f2bf(fa.x), (short)f2bf(fa.y), (short)f2bf(fa.z),
                           (short)f2bf(fa.w), (short)f2bf(fb.x), (short)f2bf(fb.y),
                           (short)f2bf(fb.z), (short)f2bf(fb.w)};
        } else {
            bfr = *(const short8*)((const u16*)xin + (size_t)nodec * K + ks * 32 + kr);
        }
#pragma unroll
        for (int t = 0; t < M / 16; t++) {
            short8 afr = *(const short8*)&lwt[(t * 16 + (lane & 15)) * LDK + ks * 32 + kr];
            acc[t] = __builtin_amdgcn_mfma_f32_16x16x32_bf16(afr, bfr, acc[t], 0, 0, 0);
        }
    }
    if (node < N) {
        float dv16 = dinv[node] * 16.0f;
        int r0 = (lane >> 4) * 4;
#pragma unroll
        for (int t = 0; t < M / 16; t++) {
            u32 w = __builtin_amdgcn_cvt_pk_fp8_f32(acc[t][0] * dv16, acc[t][1] * dv16, 0, false);
            w = __builtin_amdgcn_cvt_pk_fp8_f32(acc[t][2] * dv16, acc[t][3] * dv16, w, true);
            *(u32*)(g8 + (size_t)node * M + t * 16 + r0) = w;
        }
    }
}

// ---------- aggregation via MFMA: 2 nodes/wave, persistent waves, cross-pair pipeline
// R9/R10 counters: cost = serial trips x chain latency; per-pair prologue
// (offs/ends -> csr -> gather, ~1400cy) was fully exposed, ~1/3 of wave time.
// R11: each wave handles PPW pairs; next pair's offs/ends issue at pair start,
// next pair's first-window csr indices issue after this pair's windows. The
// compiler can't do this across the data-dependent loop (R9 showed it already
// pipelines within a pair). Outstanding gathers stay at 4 (R7 MSHR lesson).
__global__ __launch_bounds__(256) void k_agg128(const u8* __restrict__ g8,
                                                const int* __restrict__ offs,
                                                const int* __restrict__ ends,
                                                const int* __restrict__ csr,
                                                const float* __restrict__ dinv,
                                                const float* __restrict__ bias,
                                                u16* __restrict__ hout, int N, int P, int NW) {
    int wv0 = (blockIdx.x * 256 + threadIdx.x) >> 6;
    if (wv0 >= NW || wv0 >= P) return;
    int lane = threadIdx.x & 63;
    int q = lane >> 4;   // k-group: 0,1 -> node A slots; 2,3 -> node B slots
    int f = lane & 15;   // A-row: feature chunk (bytes f*8..f*8+7 of each row)
    int nn = f & 7;
    bool on = (f < 8) ? (q < 2) : (q >= 2);
    uint2 bsel;
    bsel.x = (on && nn < 4) ? (0x38u << (8 * nn)) : 0u;       // fp8 e4m3 1.0 = 0x38
    bsel.y = (on && nn >= 4) ? (0x38u << (8 * (nn - 4))) : 0u;
    const u8* gf = g8 + f * 8;
    bool isA = (q < 2);
    int qm = q & 1;
    // ---- pipeline state for pair `wp` ----
    int wp = wv0;
    int widA = wp * 2, widB = widA + 1;
    int sA = offs[widA], eA = ends[widA];
    int sB = (widB < N) ? offs[widB] : 0;
    int eB = (widB < N) ? ends[widB] : 0;
    int base0 = isA ? sA : sB;
    int p0 = csr[base0 + qm];       // first-window indices (B absent -> csr[0..7], harmless)
    int p1 = csr[base0 + 2 + qm];
    int p2 = csr[base0 + 4 + qm];
    int p3 = csr[base0 + 6 + qm];
    while (true) {
        f32x4 ac0 = {0.f, 0.f, 0.f, 0.f}, ac1 = ac0, ac2 = ac0, ac3 = ac0;
        int jA = sA, jB = sB;
        {   // first window: consume prefetched indices
            bool okA = jA < eA, okB = jB < eB;
            bool ok = isA ? okA : okB;
            int i0 = p0, i1 = p1, i2 = p2, i3 = p3;
            if (!ok) { i0 = N; i1 = N; i2 = N; i3 = N; }
            uint2 w0 = *(const uint2*)(gf + ((u32)i0 << 7));
            uint2 w1 = *(const uint2*)(gf + ((u32)i1 << 7));
            uint2 w2 = *(const uint2*)(gf + ((u32)i2 << 7));
            uint2 w3 = *(const uint2*)(gf + ((u32)i3 << 7));
            ac0 = mfma_fp8(w0, bsel, ac0);
            ac1 = mfma_fp8(w1, bsel, ac1);
            ac2 = mfma_fp8(w2, bsel, ac2);
            ac3 = mfma_fp8(w3, bsel, ac3);
            if (okA) jA += 8;
            if (okB) jB += 8;
        }
        // issue next pair's meta loads; they ride under the remaining windows
        int wpn = wp + NW;
        int sAn = 0, eAn = 0, sBn = 0, eBn = 0;
        int widAn = wpn * 2, widBn = widAn + 1;
        if (wpn < P) {
            sAn = offs[widAn]; eAn = ends[widAn];
            if (widBn < N) { sBn = offs[widBn]; eBn = ends[widBn]; }
        }
        while (jA < eA || jB < eB) {   // wave-uniform
            bool okA = jA < eA, okB = jB < eB;
            int base = isA ? jA : jB;
            bool ok = isA ? okA : okB;
            int i0 = csr[base + qm];
            int i1 = csr[base + 2 + qm];
            int i2 = csr[base + 4 + qm];
            int i3 = csr[base + 6 + qm];
            if (!ok) { i0 = N; i1 = N; i2 = N; i3 = N; }
            uint2 w0 = *(const uint2*)(gf + ((u32)i0 << 7));
            uint2 w1 = *(const uint2*)(gf + ((u32)i1 << 7));
            uint2 w2 = *(const uint2*)(gf + ((u32)i2 << 7));
            uint2 w3 = *(const uint2*)(gf + ((u32)i3 << 7));
            ac0 = mfma_fp8(w0, bsel, ac0);
            ac1 = mfma_fp8(w1, bsel, ac1);
            ac2 = mfma_fp8(w2, bsel, ac2);
            ac3 = mfma_fp8(w3, bsel, ac3);
            if (okA) jA += 8;
            if (okB) jB += 8;
        }
        // issue next pair's first-window csr indices (meta arrived during windows)
        if (wpn < P) {
            int base0n = isA ? sAn : sBn;
            p0 = csr[base0n + qm];
            p1 = csr[base0n + 2 + qm];
            p2 = csr[base0n + 4 + qm];
            p3 = csr[base0n + 6 + qm];
        }
        // epilogue for current pair
        f32x4 a = (ac0 + ac1) + (ac2 + ac3);
        int jn = lane & 15, fq = lane >> 4;
        int node = (jn < 8) ? widA : widB;
        if (node < N) {
            float sc = dinv[node] * 0.0625f;
            int bb = (jn & 7);
            u32 o0, o1;
            {
                float v0 = fmaxf(fmaf(a[0], sc, bias[(4 * fq + 0) * 8 + bb]), 0.f);
                float v1 = fmaxf(fmaf(a[1], sc, bias[(4 * fq + 1) * 8 + bb]), 0.f);
                o0 = (u32)f2bf(v0) | ((u32)f2bf(v1) << 16);
            }
            {
                float v2 = fmaxf(fmaf(a[2], sc, bias[(4 * fq + 2) * 8 + bb]), 0.f);
                float v3 = fmaxf(fmaf(a[3], sc, bias[(4 * fq + 3) * 8 + bb]), 0.f);
                o1 = (u32)f2bf(v2) | ((u32)f2bf(v3) << 16);
            }
            *(uint2*)&hout[(size_t)node * 128 + fq * 32 + bb * 4] = make_uint2(o0, o1);
        }
        if (wpn >= P) break;
        wp = wpn; widA = widAn; widB = widBn;
        sA = sAn; eA = eAn; sB = sBn; eB = eBn;
    }
}

// ---------- layer-3 aggregation + log_softmax (F=64), same persistent pipeline ----
// Nodes split by C-ROWS: A-rows 0-7 gather node A, rows 8-15 node B.
__global__ __launch_bounds__(256) void k_agg64(const u8* __restrict__ g8,
                                               const int* __restrict__ offs,
                                               const int* __restrict__ ends,
                                               const int* __restrict__ csr,
                                               const float* __restrict__ dinv,
                                               const float* __restrict__ bias,
                                               float* __restrict__ out, int N, int P, int NW) {
    __shared__ float sm[4][2][64];
    int wv0 = (blockIdx.x * 256 + threadIdx.x) >> 6;
    if (wv0 >= NW || wv0 >= P) return;
    int lane = threadIdx.x & 63;
    int wv = (int)(threadIdx.x >> 6);
    int q = lane >> 4;
    int f = lane & 15;
    bool isA = (f < 8);   // A-rows 0-7 -> node A, 8-15 -> node B
    uint2 bsel;
    bsel.x = (f < 4) ? (0x38u << (8 * f)) : 0u;
    bsel.y = (f >= 4 && f < 8) ? (0x38u << (8 * (f - 4))) : 0u;
    const u8* gf = g8 + (f & 7) * 8;
    int wp = wv0;
    int widA = wp * 2, widB = widA + 1;
    int sA = offs[widA], eA = ends[widA];
    int sB = (widB < N) ? offs[widB] : 0;
    int eB = (widB < N) ? ends[widB] : 0;
    int base0 = isA ? sA : sB;
    int p0 = csr[base0 + q];
    int p1 = csr[base0 + 4 + q];
    while (true) {
        f32x4 ac0 = {0.f, 0.f, 0.f, 0.f}, ac1 = ac0;
        int jA = sA, jB = sB;
        {   // first window from prefetched indices
            bool okA = jA < eA, okB = jB < eB;
            bool ok = isA ? okA : okB;
            int i0 = p0, i1 = p1;
            if (!ok) { i0 = N; i1 = N; }
            uint2 w0 = *(const uint2*)(gf + ((u32)i0 << 6));
            uint2 w1 = *(const uint2*)(gf + ((u32)i1 << 6));
            ac0 = mfma_fp8(w0, bsel, ac0);
            ac1 = mfma_fp8(w1, bsel, ac1);
            if (okA) jA += 8;
            if (okB) jB += 8;
        }
        int wpn = wp + NW;
        int sAn = 0, eAn = 0, sBn = 0, eBn = 0;
        int widAn = wpn * 2, widBn = widAn + 1;
        if (wpn < P) {
            sAn = offs[widAn]; eAn = ends[widAn];
            if (widBn < N) { sBn = offs[widBn]; eBn = ends[widBn]; }
        }
        while (jA < eA || jB < eB) {   // wave-uniform
            bool okA = jA < eA, okB = jB < eB;
            int base = isA ? jA : jB;
            bool ok = isA ? okA : okB;
            int i0 = csr[base + q];
            int i1 = csr[base + 4 + q];
            if (!ok) { i0 = N; i1 = N; }
            uint2 w0 = *(const uint2*)(gf + ((u32)i0 << 6));
            uint2 w1 = *(const uint2*)(gf + ((u32)i1 << 6));
            ac0 = mfma_fp8(w0, bsel, ac0);
            ac1 = mfma_fp8(w1, bsel, ac1);
            if (okA) jA += 8;
            if (okB) jB += 8;
        }
        if (wpn < P) {
            int base0n = isA ? sAn : sBn;
            p0 = csr[base0n + q];
            p1 = csr[base0n + 4 + q];
        }
        f32x4 a = ac0 + ac1;
        int jn = lane & 15, fq = lane >> 4;
        int half = fq >> 1;           // 0 = A, 1 = B
        int node = widA + half;
        bool act = (jn < 8) && (node < N);
        if (act) {
            float sc = dinv[node] * 0.0625f;
            int ch = (fq & 1);
            float v0 = fmaf(a[0], sc, bias[(4 * ch + 0) * 8 + jn]);
            float v1 = fmaf(a[1], sc, bias[(4 * ch + 1) * 8 + jn]);
            float v2 = fmaf(a[2], sc, bias[(4 * ch + 2) * 8 + jn]);
            float v3 = fmaf(a[3], sc, bias[(4 * ch + 3) * 8 + jn]);
            float m = fmaxf(fmaxf(v0, v1), fmaxf(v2, v3));
            m = fmaxf(m, __shfl_xor(m, 1, 64));
            m = fmaxf(m, __shfl_xor(m, 2, 64));
            m = fmaxf(m, __shfl_xor(m, 4, 64));
            m = fmaxf(m, __shfl_xor(m, 16, 64));
            float ss = __expf(v0 - m) + __expf(v1 - m) + __expf(v2 - m) + __expf(v3 - m);
            ss += __shfl_xor(ss, 1, 64);
            ss += __shfl_xor(ss, 2, 64);
            ss += __shfl_xor(ss, 4, 64);
            ss += __shfl_xor(ss, 16, 64);
            float lg = m + __logf(ss);
            sm[wv][half][(4 * ch + 0) * 8 + jn] = v0 - lg;
            sm[wv][half][(4 * ch + 1) * 8 + jn] = v1 - lg;
            sm[wv][half][(4 * ch + 2) * 8 + jn] = v2 - lg;
            sm[wv][half][(4 * ch + 3) * 8 + jn] = v3 - lg;
        }
        if (lane < 32) {
            int h = lane >> 4;
            int node2 = widA + h;
            if (node2 < N) {
                float4 ov = *(float4*)&sm[wv][h][(lane & 15) * 4];
                *(float4*)&out[(size_t)node2 * 64 + (lane & 15) * 4] = ov;
            }
        }
        if (wpn >= P) break;
        wp = wpn; widA = widAn; widB = widBn;
        sA = sAn; eA = eAn; sB = sBn; eB = eBn;
    }
}

extern "C" void kernel_launch(void* const* d_in, const int* in_sizes, int n_in,
                              void* d_out, int out_size, void* d_ws, size_t ws_size,
                              hipStream_t stream) {
    const float* x  = (const float*)d_in[0];
    const int*   ei = (const int*)d_in[1];
    const float* W1 = (const float*)d_in[2];
    const float* b1 = (const float*)d_in[3];
    const float* W2 = (const float*)d_in[4];
    const float* b2 = (const float*)d_in[5];
    const float* W3 = (const float*)d_in[6];
    const float* b3 = (const float*)d_in[7];
    const int N = in_sizes[0] / 128;
    const int E = in_sizes[1] / 2;
    const int NBIN = (N + 127) >> 7;  // bins of 128 dsts

    char* ws = (char*)d_ws;
    size_t o = 0;
    auto alloc = [&](size_t bytes) -> char* {
        char* p = ws + o;
        o += (bytes + 255) & ~(size_t)255;
        return p;
    };
    int*   binCnt = (int*)alloc((size_t)MAXBIN * 4);
    float* dinv   = (float*)alloc((size_t)N * 4);
    int*   offs   = (int*)alloc((size_t)N * 4);
    int*   endsA  = (int*)alloc((size_t)N * 4);
    int*   csr    = (int*)alloc(((size_t)NBIN * CSRCAP + 64) * 4);
    u16*   wt1    = (u16*)alloc(128 * 128 * 2);
    u16*   wt2    = (u16*)alloc(128 * 128 * 2);
    u16*   wt3    = (u16*)alloc(64 * 128 * 2);
    u8*    g8     = (u8*)alloc(((size_t)N + 1) * 128);  // +1: zero sentinel row
    u16*   hbuf   = (u16*)alloc((size_t)N * 128 * 2);
    u32*   binned = (u32*)hbuf;  // alias (16MB <= 25.6MB): dead before first agg write
    float* outp   = (float*)d_out;

    hipMemsetAsync(binCnt, 0, (size_t)MAXBIN * 4, stream);
    int W256 = (E + 255) / 256;  // edges per block at 256 blocks
    k_bscatter<<<256, SORT_TPB, 0, stream>>>(ei, E, W256, binCnt, binned, NBIN);
    k_bcsr<<<NBIN, 256, 0, stream>>>(binned, binCnt, N, offs, endsA, dinv, csr);
    k_wtall<<<(40960 + 255) / 256, 256, 0, stream>>>(W1, W2, W3, wt1, wt2, wt3);

    int gG = (N + 63) / 64;                 // GEMM: 64 nodes/block
    int P  = (N + 1) / 2;                   // node pairs
    int NW = (P + PPW - 1) / PPW;           // persistent agg waves (PPW pairs each)
    int gA = (NW + 3) / 4;                  // 4 waves per 256-thread block

    k_gemm<128, true ><<<gG, 256, 0, stream>>>(x,    wt1, dinv, g8, N);
    k_agg128<<<gA, 256, 0, stream>>>(g8, offs, endsA, csr, dinv, b1, hbuf, N, P, NW);
    k_gemm<128, false><<<gG, 256, 0, stream>>>(hbuf, wt2, dinv, g8, N);
    k_agg128<<<gA, 256, 0, stream>>>(g8, offs, endsA, csr, dinv, b2, hbuf, N, P, NW);
    k_gemm<64,  false><<<gG, 256, 0, stream>>>(hbuf, wt3, dinv, g8, N);
    k_agg64<<<gA, 256, 0, stream>>>(g8, offs, endsA, csr, dinv, b3, outp, N, P, NW);
}